// Round 2
// baseline (377.787 us; speedup 1.0000x reference)
//
#include <hip/hip_runtime.h>

// ShallowRBF: x(8192x2048), centers(4096x2048), beta(4096), W(1000x4096), b(1000)
// out = (exp(-beta*||x-c||) @ W^T) / rowsum + b
//
// R5: (1) gemm2 ported to the 8-phase counted-vmcnt schedule: 256x128 tile,
// BK=64, 512 thr / 8 waves (2Mx4N), 96KB dbuf LDS, chunk^(row&7) swizzle,
// boundary vmcnt(2) only. Grid = 256 blocks = exactly 1 round on 256 CUs.
// (2) rowsum fused into gemm1 epilogue (16-lane shfl reduce + f32 atomicAdd,
// zeroed in prep_norm_cast); rowsum_k kernel removed.

#define BB 8192
#define DD 2048
#define CC 4096
#define KK 1000
#define KP 1024

typedef unsigned short u16;
typedef __bf16 bf16x8 __attribute__((ext_vector_type(8)));
typedef float f32x4 __attribute__((ext_vector_type(4)));

typedef const void __attribute__((address_space(1)))* gvp_t;
typedef void __attribute__((address_space(3)))* lvp_t;

__device__ __forceinline__ u16 f2bf(float f) {
  union { float f; unsigned u; } v; v.f = f;
  return (u16)((v.u + 0x7fffu + ((v.u >> 16) & 1u)) >> 16);  // RNE
}

// ---- prep: row norms (fp32) + bf16 casts of x and centers; zero rowsum ----
__global__ void prep_norm_cast(const float* __restrict__ x, const float* __restrict__ cen,
                               u16* __restrict__ xb, u16* __restrict__ cb,
                               float* __restrict__ x2, float* __restrict__ c2,
                               float* __restrict__ rowsum) {
  int row = blockIdx.x;
  const float* src;
  u16* dst;
  float* nrm;
  if (row < BB) {
    src = x + (size_t)row * DD; dst = xb + (size_t)row * DD; nrm = x2 + row;
  } else {
    int r = row - BB;
    src = cen + (size_t)r * DD; dst = cb + (size_t)r * DD; nrm = c2 + r;
  }
  int t = threadIdx.x;
  if (row < BB && t == 0) rowsum[row] = 0.f;
  float s = 0.f;
#pragma unroll
  for (int m = 0; m < 2; ++m) {
    int idx = t + 256 * m;
    float4 v = reinterpret_cast<const float4*>(src)[idx];
    s += v.x * v.x + v.y * v.y + v.z * v.z + v.w * v.w;
    reinterpret_cast<ushort4*>(dst)[idx] =
        make_ushort4(f2bf(v.x), f2bf(v.y), f2bf(v.z), f2bf(v.w));
  }
#pragma unroll
  for (int off = 1; off < 64; off <<= 1) s += __shfl_xor(s, off);
  __shared__ float red[4];
  if ((t & 63) == 0) red[t >> 6] = s;
  __syncthreads();
  if (t == 0) *nrm = red[0] + red[1] + red[2] + red[3];
}

// ---- prep: W cast to bf16, padded to 1024 rows (zeros) ----
__global__ void prep_wcast(const float* __restrict__ W, u16* __restrict__ wb) {
  int row = blockIdx.x;  // 0..1023
  int t = threadIdx.x;
  ushort4* dst = reinterpret_cast<ushort4*>(wb + (size_t)row * CC);
  if (row < KK) {
    const float4* src = reinterpret_cast<const float4*>(W + (size_t)row * CC);
#pragma unroll
    for (int m = 0; m < 4; ++m) {
      float4 v = src[t + 256 * m];
      dst[t + 256 * m] = make_ushort4(f2bf(v.x), f2bf(v.y), f2bf(v.z), f2bf(v.w));
    }
  } else {
#pragma unroll
    for (int m = 0; m < 4; ++m) dst[t + 256 * m] = make_ushort4(0, 0, 0, 0);
  }
}

// ======================= shared schedule helpers =======================
#define SB0 __builtin_amdgcn_sched_barrier(0)
#define BARR __builtin_amdgcn_s_barrier()
#define LGKM0 asm volatile("s_waitcnt lgkmcnt(0)" ::: "memory")

// ======================= GEMM1: 256x256 8-phase =======================
// LDS/buffer (64KB): A 256x64 bf16 @0, B 256x64 @32768. Row=128B; logical
// chunk s of row r at phys chunk s^(r&7). Linear gload_lds dest +
// pre-swizzled global source.

#define ST_A(BUF, H, TILE)                                                         \
  {                                                                                \
    const u16* _s = gA0 + (size_t)((H) * 128) * DD + (TILE) * 64;                  \
    char* _d = (char*)smem + (BUF) * 65536 + (H) * 16384 + t * 16;                 \
    __builtin_amdgcn_global_load_lds((gvp_t)_s, (lvp_t)_d, 16, 0, 0);              \
    __builtin_amdgcn_global_load_lds((gvp_t)(_s + (size_t)64 * DD),                \
                                     (lvp_t)(_d + 8192), 16, 0, 0);                \
  }

#define ST_B(BUF, H, TILE)                                                         \
  {                                                                                \
    const u16* _s = gB0 + (size_t)((H) * 128) * DD + (TILE) * 64;                  \
    char* _d = (char*)smem + (BUF) * 65536 + 32768 + (H) * 16384 + t * 16;         \
    __builtin_amdgcn_global_load_lds((gvp_t)_s, (lvp_t)_d, 16, 0, 0);              \
    __builtin_amdgcn_global_load_lds((gvp_t)(_s + (size_t)64 * DD),                \
                                     (lvp_t)(_d + 8192), 16, 0, 0);                \
  }

#define READ_B(SBP)                                                                \
  _Pragma("unroll") for (int n_ = 0; n_ < 4; ++n_) {                               \
    _Pragma("unroll") for (int ks_ = 0; ks_ < 2; ++ks_) {                          \
      bfr[n_][ks_] = *(const bf16x8*)((SBP) + bRow + n_ * 2048 + cbv[ks_]);        \
    }                                                                              \
  }

#define READ_A(SAP, MQ)                                                            \
  _Pragma("unroll") for (int m_ = 0; m_ < 2; ++m_) {                               \
    _Pragma("unroll") for (int ks_ = 0; ks_ < 2; ++ks_) {                          \
      af[m_][ks_] =                                                                \
          *(const bf16x8*)((SAP) + aRow + ((MQ)*2 + m_) * 2048 + cbv[ks_]);        \
    }                                                                              \
  }

#define MFMA_Q(MQ)                                                                 \
  __builtin_amdgcn_s_setprio(1);                                                   \
  _Pragma("unroll") for (int m_ = 0; m_ < 2; ++m_) {                               \
    _Pragma("unroll") for (int n_ = 0; n_ < 4; ++n_) {                             \
      _Pragma("unroll") for (int ks_ = 0; ks_ < 2; ++ks_) {                        \
        acc[(MQ)*2 + m_][n_] = __builtin_amdgcn_mfma_f32_16x16x32_bf16(            \
            af[m_][ks_], bfr[n_][ks_], acc[(MQ)*2 + m_][n_], 0, 0, 0);             \
      }                                                                            \
    }                                                                              \
  }                                                                                \
  __builtin_amdgcn_s_setprio(0)

#define TILE_BODY(TILE, CUR, DOA, DOB, VMN)                                        \
  {                                                                                \
    const char* sA_ = (const char*)smem + (CUR) * 65536;                           \
    const char* sB_ = sA_ + 32768;                                                 \
    READ_B(sB_);                                                                   \
    READ_A(sA_, 0);                                                                \
    SB0;                                                                           \
    if (DOA) { ST_A(1 - (CUR), 0, (TILE) + 1); ST_A(1 - (CUR), 1, (TILE) + 1); }   \
    SB0; BARR; LGKM0; SB0;                                                         \
    MFMA_Q(0); SB0; BARR;                                                          \
    READ_A(sA_, 1); SB0;                                                           \
    if (DOB) { ST_B((CUR), 0, (TILE) + 2); }                                       \
    SB0; BARR; LGKM0; SB0;                                                         \
    MFMA_Q(1); SB0; BARR;                                                          \
    READ_A(sA_, 2); SB0;                                                           \
    if (DOB) { ST_B((CUR), 1, (TILE) + 2); }                                       \
    SB0; BARR; LGKM0; SB0;                                                         \
    MFMA_Q(2); SB0; BARR;                                                          \
    READ_A(sA_, 3); SB0; BARR; LGKM0; SB0;                                         \
    MFMA_Q(3);                                                                     \
    if ((VMN) == 4) { asm volatile("s_waitcnt vmcnt(4)" ::: "memory"); }           \
    else if ((VMN) == 0) { asm volatile("s_waitcnt vmcnt(0)" ::: "memory"); }      \
    SB0; BARR;                                                                     \
  }

__global__ __launch_bounds__(512, 2)
void gemm1_rbf(const u16* __restrict__ Abf, const u16* __restrict__ Bbf,
               const float* __restrict__ x2, const float* __restrict__ c2,
               const float* __restrict__ beta, u16* __restrict__ Ebf,
               float* __restrict__ rowsum) {
  constexpr int NT = DD / 64;  // 32 K-tiles
  __shared__ __align__(16) char smem[131072];

  const int t = threadIdx.x;
  const int lane = t & 63;
  const int wave = t >> 6;
  const int wr = wave >> 2;  // 0..1: rows wr*128..
  const int wc = wave & 3;   // 0..3: cols wc*64..
  const int l15 = lane & 15;

  const int rowBase = blockIdx.y * 256;
  const int colBase = blockIdx.x * 256;

  f32x4 acc[8][4];
#pragma unroll
  for (int i = 0; i < 8; ++i)
#pragma unroll
    for (int j = 0; j < 4; ++j) acc[i][j] = 0.f;

  // staging source (pre-swizzled logical chunk)
  const int srow = t >> 3;
  const u16* gA0 = Abf + (size_t)(rowBase + srow) * DD + ((t & 7) ^ (srow & 7)) * 8;
  const u16* gB0 = Bbf + (size_t)(colBase + srow) * DD + ((t & 7) ^ (srow & 7)) * 8;

  // frag-read byte column per kstep: phys chunk = (ks*4 + l>>4) ^ (l&7)
  int cbv[2];
  cbv[0] = (((lane >> 4) & 3) ^ (lane & 7)) << 4;
  cbv[1] = ((4 + ((lane >> 4) & 3)) ^ (lane & 7)) << 4;
  const int aRow = (wr * 128 + l15) * 128;
  const int bRow = (wc * 64 + l15) * 128;

  bf16x8 bfr[4][2];
  bf16x8 af[2][2];

  // prologue: tile0 complete + tile1 B-halves in flight
  ST_A(0, 0, 0); ST_A(0, 1, 0); ST_B(0, 0, 0); ST_B(0, 1, 0);
  ST_B(1, 0, 1); ST_B(1, 1, 1);
  asm volatile("s_waitcnt vmcnt(4)" ::: "memory");
  BARR;

#pragma unroll 2
  for (int tile = 0; tile < NT - 2; ++tile) {
    TILE_BODY(tile, tile & 1, true, true, 4);
  }
  TILE_BODY(NT - 2, (NT - 2) & 1, true, false, 0);
  TILE_BODY(NT - 1, (NT - 1) & 1, false, false, -1);

  // epilogue: C/D layout (16x16): col = lane&15, row = (lane>>4)*4 + reg
  const int khi4 = (lane >> 4) * 4;
  float c2v[4], bet[4];
  int gc[4];
#pragma unroll
  for (int n = 0; n < 4; ++n) {
    gc[n] = colBase + wc * 64 + n * 16 + l15;
    c2v[n] = c2[gc[n]];
    bet[n] = beta[gc[n]];
  }
#pragma unroll
  for (int m = 0; m < 8; ++m) {
#pragma unroll
    for (int r = 0; r < 4; ++r) {
      const int grow = rowBase + wr * 128 + m * 16 + khi4 + r;
      const float x2v = x2[grow];
      u16* orow = Ebf + (size_t)grow * CC;
      float rs = 0.f;
#pragma unroll
      for (int n = 0; n < 4; ++n) {
        float d = acc[m][n][r];
        float sq = fmaxf(x2v + c2v[n] - 2.0f * d, 0.0f);
        float e = __expf(-bet[n] * __builtin_amdgcn_sqrtf(sq));
        rs += e;
        orow[gc[n]] = f2bf(e);
      }
      // fused rowsum partial: reduce over the 16 lanes sharing this row
#pragma unroll
      for (int off = 1; off < 16; off <<= 1) rs += __shfl_xor(rs, off);
      if (l15 == 0) atomicAdd(&rowsum[grow], rs);
    }
  }
}

// ============ GEMM2: 256x128 8-phase; out = (E @ W^T)/rowsum + bias ============
// LDS/buffer (48KB): A 256x64 bf16 (32KB) @0, B 128x64 (16KB) @32768.
// Same swizzle. Staging: A-halves of t+1 at ph0/ph1, B of t+2 at ph2;
// boundary vmcnt(2). Per-wave out 128x32 (2Mx4N waves), 8 MFMA/phase.

#define ST2_A(BUF, H, TILE)                                                        \
  {                                                                                \
    const u16* _s = gA0 + (size_t)((H) * 128) * CC + (TILE) * 64;                  \
    char* _d = (char*)smem + (BUF) * 49152 + (H) * 16384 + t * 16;                 \
    __builtin_amdgcn_global_load_lds((gvp_t)_s, (lvp_t)_d, 16, 0, 0);              \
    __builtin_amdgcn_global_load_lds((gvp_t)(_s + (size_t)64 * CC),                \
                                     (lvp_t)(_d + 8192), 16, 0, 0);                \
  }

#define ST2_B(BUF, TILE)                                                           \
  {                                                                                \
    const u16* _s = gB0 + (TILE) * 64;                                             \
    char* _d = (char*)smem + (BUF) * 49152 + 32768 + t * 16;                       \
    __builtin_amdgcn_global_load_lds((gvp_t)_s, (lvp_t)_d, 16, 0, 0);              \
    __builtin_amdgcn_global_load_lds((gvp_t)(_s + (size_t)64 * CC),                \
                                     (lvp_t)(_d + 8192), 16, 0, 0);                \
  }

#define READ2_B(SBP)                                                               \
  _Pragma("unroll") for (int n_ = 0; n_ < 2; ++n_) {                               \
    _Pragma("unroll") for (int ks_ = 0; ks_ < 2; ++ks_) {                          \
      bfr[n_][ks_] = *(const bf16x8*)((SBP) + bRow + n_ * 2048 + cbv[ks_]);        \
    }                                                                              \
  }

#define READ2_A(SAP, MQ)                                                           \
  _Pragma("unroll") for (int m_ = 0; m_ < 2; ++m_) {                               \
    _Pragma("unroll") for (int ks_ = 0; ks_ < 2; ++ks_) {                          \
      af[m_][ks_] =                                                                \
          *(const bf16x8*)((SAP) + aRow + ((MQ)*2 + m_) * 2048 + cbv[ks_]);        \
    }                                                                              \
  }

#define MFMA2_Q(MQ)                                                                \
  __builtin_amdgcn_s_setprio(1);                                                   \
  _Pragma("unroll") for (int m_ = 0; m_ < 2; ++m_) {                               \
    _Pragma("unroll") for (int n_ = 0; n_ < 2; ++n_) {                             \
      _Pragma("unroll") for (int ks_ = 0; ks_ < 2; ++ks_) {                        \
        acc[(MQ)*2 + m_][n_] = __builtin_amdgcn_mfma_f32_16x16x32_bf16(            \
            af[m_][ks_], bfr[n_][ks_], acc[(MQ)*2 + m_][n_], 0, 0, 0);             \
      }                                                                            \
    }                                                                              \
  }                                                                                \
  __builtin_amdgcn_s_setprio(0)

#define TILE2_BODY(TILE, CUR, DOA, DOB, VMN)                                       \
  {                                                                                \
    const char* sA_ = (const char*)smem + (CUR) * 49152;                           \
    const char* sB_ = sA_ + 32768;                                                 \
    READ2_B(sB_);                                                                  \
    READ2_A(sA_, 0);                                                               \
    SB0;                                                                           \
    if (DOA) { ST2_A(1 - (CUR), 0, (TILE) + 1); }                                  \
    SB0; BARR; LGKM0; SB0;                                                         \
    MFMA2_Q(0); SB0; BARR;                                                         \
    READ2_A(sA_, 1); SB0;                                                          \
    if (DOA) { ST2_A(1 - (CUR), 1, (TILE) + 1); }                                  \
    SB0; BARR; LGKM0; SB0;                                                         \
    MFMA2_Q(1); SB0; BARR;                                                         \
    READ2_A(sA_, 2); SB0;                                                          \
    if (DOB) { ST2_B((CUR), (TILE) + 2); }                                         \
    SB0; BARR; LGKM0; SB0;                                                         \
    MFMA2_Q(2); SB0; BARR;                                                         \
    READ2_A(sA_, 3); SB0; BARR; LGKM0; SB0;                                        \
    MFMA2_Q(3);                                                                    \
    if ((VMN) == 2) { asm volatile("s_waitcnt vmcnt(2)" ::: "memory"); }           \
    else if ((VMN) == 0) { asm volatile("s_waitcnt vmcnt(0)" ::: "memory"); }      \
    SB0; BARR;                                                                     \
  }

__global__ __launch_bounds__(512, 2)
void gemm2_out(const u16* __restrict__ Ebf, const u16* __restrict__ Wbf,
               const float* __restrict__ rowsum, const float* __restrict__ bias,
               float* __restrict__ out) {
  constexpr int NT = CC / 64;  // 64 K-tiles
  __shared__ __align__(16) char smem[98304];

  const int t = threadIdx.x;
  const int lane = t & 63;
  const int wave = t >> 6;
  const int wr = wave >> 2;  // 0..1: rows wr*128..
  const int wc = wave & 3;   // 0..3: cols wc*32..
  const int l15 = lane & 15;

  const int rowBase = blockIdx.y * 256;
  const int colBase = blockIdx.x * 128;

  f32x4 acc[8][2];
#pragma unroll
  for (int i = 0; i < 8; ++i)
#pragma unroll
    for (int j = 0; j < 2; ++j) acc[i][j] = 0.f;

  const int srow = t >> 3;
  const u16* gA0 = Ebf + (size_t)(rowBase + srow) * CC + ((t & 7) ^ (srow & 7)) * 8;
  const u16* gB0 = Wbf + (size_t)(colBase + srow) * CC + ((t & 7) ^ (srow & 7)) * 8;

  int cbv[2];
  cbv[0] = (((lane >> 4) & 3) ^ (lane & 7)) << 4;
  cbv[1] = ((4 + ((lane >> 4) & 3)) ^ (lane & 7)) << 4;
  const int aRow = (wr * 128 + l15) * 128;
  const int bRow = (wc * 32 + l15) * 128;

  bf16x8 bfr[2][2];
  bf16x8 af[2][2];

  // prologue: tile0 A+B complete, tile1 B in flight
  ST2_A(0, 0, 0); ST2_A(0, 1, 0); ST2_B(0, 0);
  ST2_B(1, 1);
  asm volatile("s_waitcnt vmcnt(2)" ::: "memory");
  BARR;

#pragma unroll 2
  for (int tile = 0; tile < NT - 2; ++tile) {
    TILE2_BODY(tile, tile & 1, true, true, 2);
  }
  TILE2_BODY(NT - 2, (NT - 2) & 1, true, false, 0);
  TILE2_BODY(NT - 1, (NT - 1) & 1, false, false, -1);

  // epilogue
  const int khi4 = (lane >> 4) * 4;
  int gc[2];
  float bv[2];
#pragma unroll
  for (int n = 0; n < 2; ++n) {
    gc[n] = colBase + wc * 32 + n * 16 + l15;
    bv[n] = (gc[n] < KK) ? bias[gc[n]] : 0.f;
  }
#pragma unroll
  for (int m = 0; m < 8; ++m) {
#pragma unroll
    for (int r = 0; r < 4; ++r) {
      const int grow = rowBase + wr * 128 + m * 16 + khi4 + r;
      const float inv = 1.0f / rowsum[grow];
#pragma unroll
      for (int n = 0; n < 2; ++n) {
        if (gc[n] < KK)
          out[(size_t)grow * KK + gc[n]] = acc[m][n][r] * inv + bv[n];
      }
    }
  }
}

// ---- workspace layout (bytes) ----
#define OFF_XB 0u                    // 8192*2048*2 = 33554432
#define OFF_CB 33554432u             // 4096*2048*2 = 16777216
#define OFF_WB 50331648u             // 1024*4096*2 = 8388608
#define OFF_EB 58720256u             // 8192*4096*2 = 67108864
#define OFF_X2 125829120u            // 8192*4
#define OFF_C2 125861888u            // 4096*4
#define OFF_RS 125878272u            // 8192*4

extern "C" void kernel_launch(void* const* d_in, const int* in_sizes, int n_in,
                              void* d_out, int out_size, void* d_ws, size_t ws_size,
                              hipStream_t stream) {
  const float* x = (const float*)d_in[0];
  const float* cen = (const float*)d_in[1];
  const float* beta = (const float*)d_in[2];
  const float* W = (const float*)d_in[3];
  const float* bias = (const float*)d_in[4];
  float* out = (float*)d_out;
  char* ws = (char*)d_ws;

  u16* xb = (u16*)(ws + OFF_XB);
  u16* cb = (u16*)(ws + OFF_CB);
  u16* wb = (u16*)(ws + OFF_WB);
  u16* eb = (u16*)(ws + OFF_EB);
  float* x2 = (float*)(ws + OFF_X2);
  float* c2 = (float*)(ws + OFF_C2);
  float* rowsum = (float*)(ws + OFF_RS);

  prep_norm_cast<<<BB + CC, 256, 0, stream>>>(x, cen, xb, cb, x2, c2, rowsum);
  prep_wcast<<<KP, 256, 0, stream>>>(W, wb);
  gemm1_rbf<<<dim3(CC / 256, BB / 256), 512, 0, stream>>>(xb, cb, x2, c2, beta, eb, rowsum);
  gemm2_out<<<dim3(KP / 128, BB / 256), 512, 0, stream>>>(eb, wb, rowsum, bias, out);
}

// Round 3
// 354.520 us; speedup vs baseline: 1.0656x; 1.0656x over previous
//
#include <hip/hip_runtime.h>

// ShallowRBF: x(8192x2048), centers(4096x2048), beta(4096), W(1000x4096), b(1000)
// out = (exp(-beta*||x-c||) @ W^T) / rowsum + b
//
// R6: (1) gemm1 epilogue reverted to R4 (no atomics - R5's fused-rowsum
// atomicAdd contention cost +40us). (2) rowsum computed inside gemm2 via
// ones-MFMA: rsacc = mfma(af, ones, rsacc) accumulates sum_k E[row,k] on the
// MFMA pipe (gemm2's K covers all 4096 centers); C/D layout puts rsacc[m][r]
// on exactly the epilogue lane that needs it -> inv = 1/rsacc[m][r], no
// shuffles/LDS/atomics. (3) prep kernels fused (3 launches total).

#define BB 8192
#define DD 2048
#define CC 4096
#define KK 1000
#define KP 1024

typedef unsigned short u16;
typedef __bf16 bf16x8 __attribute__((ext_vector_type(8)));
typedef float f32x4 __attribute__((ext_vector_type(4)));

typedef const void __attribute__((address_space(1)))* gvp_t;
typedef void __attribute__((address_space(3)))* lvp_t;

__device__ __forceinline__ u16 f2bf(float f) {
  union { float f; unsigned u; } v; v.f = f;
  return (u16)((v.u + 0x7fffu + ((v.u >> 16) & 1u)) >> 16);  // RNE
}

// ---- prep (fused): row norms + bf16 casts of x, centers; W cast+pad ----
__global__ void prep_all(const float* __restrict__ x, const float* __restrict__ cen,
                         const float* __restrict__ W,
                         u16* __restrict__ xb, u16* __restrict__ cb,
                         u16* __restrict__ wb,
                         float* __restrict__ x2, float* __restrict__ c2) {
  int row = blockIdx.x;
  int t = threadIdx.x;
  if (row >= BB + CC) {  // W rows (padded to KP with zeros)
    int r = row - BB - CC;
    ushort4* dst = reinterpret_cast<ushort4*>(wb + (size_t)r * CC);
    if (r < KK) {
      const float4* src = reinterpret_cast<const float4*>(W + (size_t)r * CC);
#pragma unroll
      for (int m = 0; m < 4; ++m) {
        float4 v = src[t + 256 * m];
        dst[t + 256 * m] = make_ushort4(f2bf(v.x), f2bf(v.y), f2bf(v.z), f2bf(v.w));
      }
    } else {
#pragma unroll
      for (int m = 0; m < 4; ++m) dst[t + 256 * m] = make_ushort4(0, 0, 0, 0);
    }
    return;
  }
  const float* src;
  u16* dst;
  float* nrm;
  if (row < BB) {
    src = x + (size_t)row * DD; dst = xb + (size_t)row * DD; nrm = x2 + row;
  } else {
    int r = row - BB;
    src = cen + (size_t)r * DD; dst = cb + (size_t)r * DD; nrm = c2 + r;
  }
  float s = 0.f;
#pragma unroll
  for (int m = 0; m < 2; ++m) {
    int idx = t + 256 * m;
    float4 v = reinterpret_cast<const float4*>(src)[idx];
    s += v.x * v.x + v.y * v.y + v.z * v.z + v.w * v.w;
    reinterpret_cast<ushort4*>(dst)[idx] =
        make_ushort4(f2bf(v.x), f2bf(v.y), f2bf(v.z), f2bf(v.w));
  }
#pragma unroll
  for (int off = 1; off < 64; off <<= 1) s += __shfl_xor(s, off);
  __shared__ float red[4];
  if ((t & 63) == 0) red[t >> 6] = s;
  __syncthreads();
  if (t == 0) *nrm = red[0] + red[1] + red[2] + red[3];
}

// ======================= shared schedule helpers =======================
#define SB0 __builtin_amdgcn_sched_barrier(0)
#define BARR __builtin_amdgcn_s_barrier()
#define LGKM0 asm volatile("s_waitcnt lgkmcnt(0)" ::: "memory")

// ======================= GEMM1: 256x256 8-phase =======================
// LDS/buffer (64KB): A 256x64 bf16 @0, B 256x64 @32768. Row=128B; logical
// chunk s of row r at phys chunk s^(r&7). Linear gload_lds dest +
// pre-swizzled global source.

#define ST_A(BUF, H, TILE)                                                         \
  {                                                                                \
    const u16* _s = gA0 + (size_t)((H) * 128) * DD + (TILE) * 64;                  \
    char* _d = (char*)smem + (BUF) * 65536 + (H) * 16384 + t * 16;                 \
    __builtin_amdgcn_global_load_lds((gvp_t)_s, (lvp_t)_d, 16, 0, 0);              \
    __builtin_amdgcn_global_load_lds((gvp_t)(_s + (size_t)64 * DD),                \
                                     (lvp_t)(_d + 8192), 16, 0, 0);                \
  }

#define ST_B(BUF, H, TILE)                                                         \
  {                                                                                \
    const u16* _s = gB0 + (size_t)((H) * 128) * DD + (TILE) * 64;                  \
    char* _d = (char*)smem + (BUF) * 65536 + 32768 + (H) * 16384 + t * 16;         \
    __builtin_amdgcn_global_load_lds((gvp_t)_s, (lvp_t)_d, 16, 0, 0);              \
    __builtin_amdgcn_global_load_lds((gvp_t)(_s + (size_t)64 * DD),                \
                                     (lvp_t)(_d + 8192), 16, 0, 0);                \
  }

#define READ_B(SBP)                                                                \
  _Pragma("unroll") for (int n_ = 0; n_ < 4; ++n_) {                               \
    _Pragma("unroll") for (int ks_ = 0; ks_ < 2; ++ks_) {                          \
      bfr[n_][ks_] = *(const bf16x8*)((SBP) + bRow + n_ * 2048 + cbv[ks_]);        \
    }                                                                              \
  }

#define READ_A(SAP, MQ)                                                            \
  _Pragma("unroll") for (int m_ = 0; m_ < 2; ++m_) {                               \
    _Pragma("unroll") for (int ks_ = 0; ks_ < 2; ++ks_) {                          \
      af[m_][ks_] =                                                                \
          *(const bf16x8*)((SAP) + aRow + ((MQ)*2 + m_) * 2048 + cbv[ks_]);        \
    }                                                                              \
  }

#define MFMA_Q(MQ)                                                                 \
  __builtin_amdgcn_s_setprio(1);                                                   \
  _Pragma("unroll") for (int m_ = 0; m_ < 2; ++m_) {                               \
    _Pragma("unroll") for (int n_ = 0; n_ < 4; ++n_) {                             \
      _Pragma("unroll") for (int ks_ = 0; ks_ < 2; ++ks_) {                        \
        acc[(MQ)*2 + m_][n_] = __builtin_amdgcn_mfma_f32_16x16x32_bf16(            \
            af[m_][ks_], bfr[n_][ks_], acc[(MQ)*2 + m_][n_], 0, 0, 0);             \
      }                                                                            \
    }                                                                              \
  }                                                                                \
  __builtin_amdgcn_s_setprio(0)

#define TILE_BODY(TILE, CUR, DOA, DOB, VMN)                                        \
  {                                                                                \
    const char* sA_ = (const char*)smem + (CUR) * 65536;                           \
    const char* sB_ = sA_ + 32768;                                                 \
    READ_B(sB_);                                                                   \
    READ_A(sA_, 0);                                                                \
    SB0;                                                                           \
    if (DOA) { ST_A(1 - (CUR), 0, (TILE) + 1); ST_A(1 - (CUR), 1, (TILE) + 1); }   \
    SB0; BARR; LGKM0; SB0;                                                         \
    MFMA_Q(0); SB0; BARR;                                                          \
    READ_A(sA_, 1); SB0;                                                           \
    if (DOB) { ST_B((CUR), 0, (TILE) + 2); }                                       \
    SB0; BARR; LGKM0; SB0;                                                         \
    MFMA_Q(1); SB0; BARR;                                                          \
    READ_A(sA_, 2); SB0;                                                           \
    if (DOB) { ST_B((CUR), 1, (TILE) + 2); }                                       \
    SB0; BARR; LGKM0; SB0;                                                         \
    MFMA_Q(2); SB0; BARR;                                                          \
    READ_A(sA_, 3); SB0; BARR; LGKM0; SB0;                                         \
    MFMA_Q(3);                                                                     \
    if ((VMN) == 4) { asm volatile("s_waitcnt vmcnt(4)" ::: "memory"); }           \
    else if ((VMN) == 0) { asm volatile("s_waitcnt vmcnt(0)" ::: "memory"); }      \
    SB0; BARR;                                                                     \
  }

__global__ __launch_bounds__(512, 2)
void gemm1_rbf(const u16* __restrict__ Abf, const u16* __restrict__ Bbf,
               const float* __restrict__ x2, const float* __restrict__ c2,
               const float* __restrict__ beta, u16* __restrict__ Ebf) {
  constexpr int NT = DD / 64;  // 32 K-tiles
  __shared__ __align__(16) char smem[131072];

  const int t = threadIdx.x;
  const int lane = t & 63;
  const int wave = t >> 6;
  const int wr = wave >> 2;  // 0..1: rows wr*128..
  const int wc = wave & 3;   // 0..3: cols wc*64..
  const int l15 = lane & 15;

  const int rowBase = blockIdx.y * 256;
  const int colBase = blockIdx.x * 256;

  f32x4 acc[8][4];
#pragma unroll
  for (int i = 0; i < 8; ++i)
#pragma unroll
    for (int j = 0; j < 4; ++j) acc[i][j] = 0.f;

  // staging source (pre-swizzled logical chunk)
  const int srow = t >> 3;
  const u16* gA0 = Abf + (size_t)(rowBase + srow) * DD + ((t & 7) ^ (srow & 7)) * 8;
  const u16* gB0 = Bbf + (size_t)(colBase + srow) * DD + ((t & 7) ^ (srow & 7)) * 8;

  // frag-read byte column per kstep: phys chunk = (ks*4 + l>>4) ^ (l&7)
  int cbv[2];
  cbv[0] = (((lane >> 4) & 3) ^ (lane & 7)) << 4;
  cbv[1] = ((4 + ((lane >> 4) & 3)) ^ (lane & 7)) << 4;
  const int aRow = (wr * 128 + l15) * 128;
  const int bRow = (wc * 64 + l15) * 128;

  bf16x8 bfr[4][2];
  bf16x8 af[2][2];

  // prologue: tile0 complete + tile1 B-halves in flight
  ST_A(0, 0, 0); ST_A(0, 1, 0); ST_B(0, 0, 0); ST_B(0, 1, 0);
  ST_B(1, 0, 1); ST_B(1, 1, 1);
  asm volatile("s_waitcnt vmcnt(4)" ::: "memory");
  BARR;

#pragma unroll 2
  for (int tile = 0; tile < NT - 2; ++tile) {
    TILE_BODY(tile, tile & 1, true, true, 4);
  }
  TILE_BODY(NT - 2, (NT - 2) & 1, true, false, 0);
  TILE_BODY(NT - 1, (NT - 1) & 1, false, false, -1);

  // epilogue: C/D layout (16x16): col = lane&15, row = (lane>>4)*4 + reg
  const int khi4 = (lane >> 4) * 4;
  float c2v[4], bet[4];
  int gc[4];
#pragma unroll
  for (int n = 0; n < 4; ++n) {
    gc[n] = colBase + wc * 64 + n * 16 + l15;
    c2v[n] = c2[gc[n]];
    bet[n] = beta[gc[n]];
  }
#pragma unroll
  for (int m = 0; m < 8; ++m) {
#pragma unroll
    for (int r = 0; r < 4; ++r) {
      const int grow = rowBase + wr * 128 + m * 16 + khi4 + r;
      const float x2v = x2[grow];
      u16* orow = Ebf + (size_t)grow * CC;
#pragma unroll
      for (int n = 0; n < 4; ++n) {
        float d = acc[m][n][r];
        float sq = fmaxf(x2v + c2v[n] - 2.0f * d, 0.0f);
        float e = __expf(-bet[n] * __builtin_amdgcn_sqrtf(sq));
        orow[gc[n]] = f2bf(e);
      }
    }
  }
}

// ============ GEMM2: 256x128 8-phase; out = (E @ W^T)/rowsum + bias ============
// LDS/buffer (48KB): A 256x64 bf16 (32KB) @0, B 128x64 (16KB) @32768.
// Same swizzle. Staging: A-halves of t+1 at ph0/ph1, B of t+2 at ph2;
// boundary vmcnt(2). Per-wave out 128x32 (2Mx4N waves), 8+4 MFMA/phase
// (4 extra = ones-MFMA rowsum accumulation).

#define ST2_A(BUF, H, TILE)                                                        \
  {                                                                                \
    const u16* _s = gA0 + (size_t)((H) * 128) * CC + (TILE) * 64;                  \
    char* _d = (char*)smem + (BUF) * 49152 + (H) * 16384 + t * 16;                 \
    __builtin_amdgcn_global_load_lds((gvp_t)_s, (lvp_t)_d, 16, 0, 0);              \
    __builtin_amdgcn_global_load_lds((gvp_t)(_s + (size_t)64 * CC),                \
                                     (lvp_t)(_d + 8192), 16, 0, 0);                \
  }

#define ST2_B(BUF, TILE)                                                           \
  {                                                                                \
    const u16* _s = gB0 + (TILE) * 64;                                             \
    char* _d = (char*)smem + (BUF) * 49152 + 32768 + t * 16;                       \
    __builtin_amdgcn_global_load_lds((gvp_t)_s, (lvp_t)_d, 16, 0, 0);              \
    __builtin_amdgcn_global_load_lds((gvp_t)(_s + (size_t)64 * CC),                \
                                     (lvp_t)(_d + 8192), 16, 0, 0);                \
  }

#define READ2_B(SBP)                                                               \
  _Pragma("unroll") for (int n_ = 0; n_ < 2; ++n_) {                               \
    _Pragma("unroll") for (int ks_ = 0; ks_ < 2; ++ks_) {                          \
      bfr[n_][ks_] = *(const bf16x8*)((SBP) + bRow + n_ * 2048 + cbv[ks_]);        \
    }                                                                              \
  }

#define READ2_A(SAP, MQ)                                                           \
  _Pragma("unroll") for (int m_ = 0; m_ < 2; ++m_) {                               \
    _Pragma("unroll") for (int ks_ = 0; ks_ < 2; ++ks_) {                          \
      af[m_][ks_] =                                                                \
          *(const bf16x8*)((SAP) + aRow + ((MQ)*2 + m_) * 2048 + cbv[ks_]);        \
    }                                                                              \
  }

// 8 product MFMAs + 4 ones-MFMAs (rowsum) per phase, all in the setprio region.
#define MFMA2_Q(MQ)                                                                \
  __builtin_amdgcn_s_setprio(1);                                                   \
  _Pragma("unroll") for (int m_ = 0; m_ < 2; ++m_) {                               \
    _Pragma("unroll") for (int n_ = 0; n_ < 2; ++n_) {                             \
      _Pragma("unroll") for (int ks_ = 0; ks_ < 2; ++ks_) {                        \
        acc[(MQ)*2 + m_][n_] = __builtin_amdgcn_mfma_f32_16x16x32_bf16(            \
            af[m_][ks_], bfr[n_][ks_], acc[(MQ)*2 + m_][n_], 0, 0, 0);             \
      }                                                                            \
    }                                                                              \
  }                                                                                \
  _Pragma("unroll") for (int m_ = 0; m_ < 2; ++m_) {                               \
    _Pragma("unroll") for (int ks_ = 0; ks_ < 2; ++ks_) {                          \
      rsacc[(MQ)*2 + m_] = __builtin_amdgcn_mfma_f32_16x16x32_bf16(                \
          af[m_][ks_], onesf, rsacc[(MQ)*2 + m_], 0, 0, 0);                        \
    }                                                                              \
  }                                                                                \
  __builtin_amdgcn_s_setprio(0)

#define TILE2_BODY(TILE, CUR, DOA, DOB, VMN)                                       \
  {                                                                                \
    const char* sA_ = (const char*)smem + (CUR) * 49152;                           \
    const char* sB_ = sA_ + 32768;                                                 \
    READ2_B(sB_);                                                                  \
    READ2_A(sA_, 0);                                                               \
    SB0;                                                                           \
    if (DOA) { ST2_A(1 - (CUR), 0, (TILE) + 1); }                                  \
    SB0; BARR; LGKM0; SB0;                                                         \
    MFMA2_Q(0); SB0; BARR;                                                         \
    READ2_A(sA_, 1); SB0;                                                          \
    if (DOA) { ST2_A(1 - (CUR), 1, (TILE) + 1); }                                  \
    SB0; BARR; LGKM0; SB0;                                                         \
    MFMA2_Q(1); SB0; BARR;                                                         \
    READ2_A(sA_, 2); SB0;                                                          \
    if (DOB) { ST2_B((CUR), (TILE) + 2); }                                         \
    SB0; BARR; LGKM0; SB0;                                                         \
    MFMA2_Q(2); SB0; BARR;                                                         \
    READ2_A(sA_, 3); SB0; BARR; LGKM0; SB0;                                        \
    MFMA2_Q(3);                                                                    \
    if ((VMN) == 2) { asm volatile("s_waitcnt vmcnt(2)" ::: "memory"); }           \
    else if ((VMN) == 0) { asm volatile("s_waitcnt vmcnt(0)" ::: "memory"); }      \
    SB0; BARR;                                                                     \
  }

__global__ __launch_bounds__(512, 2)
void gemm2_out(const u16* __restrict__ Ebf, const u16* __restrict__ Wbf,
               const float* __restrict__ bias, float* __restrict__ out) {
  constexpr int NT = CC / 64;  // 64 K-tiles
  __shared__ __align__(16) char smem[98304];

  const int t = threadIdx.x;
  const int lane = t & 63;
  const int wave = t >> 6;
  const int wr = wave >> 2;  // 0..1: rows wr*128..
  const int wc = wave & 3;   // 0..3: cols wc*32..
  const int l15 = lane & 15;

  const int rowBase = blockIdx.y * 256;
  const int colBase = blockIdx.x * 128;

  f32x4 acc[8][2];
#pragma unroll
  for (int i = 0; i < 8; ++i)
#pragma unroll
    for (int j = 0; j < 2; ++j) acc[i][j] = 0.f;

  // ones-MFMA rowsum state: rsacc[m] row-matches acc[m] (same A fragments)
  f32x4 rsacc[8];
#pragma unroll
  for (int i = 0; i < 8; ++i) rsacc[i] = 0.f;
  bf16x8 onesf;
#pragma unroll
  for (int e = 0; e < 8; ++e) onesf[e] = (__bf16)1.0f;

  const int srow = t >> 3;
  const u16* gA0 = Ebf + (size_t)(rowBase + srow) * CC + ((t & 7) ^ (srow & 7)) * 8;
  const u16* gB0 = Wbf + (size_t)(colBase + srow) * CC + ((t & 7) ^ (srow & 7)) * 8;

  int cbv[2];
  cbv[0] = (((lane >> 4) & 3) ^ (lane & 7)) << 4;
  cbv[1] = ((4 + ((lane >> 4) & 3)) ^ (lane & 7)) << 4;
  const int aRow = (wr * 128 + l15) * 128;
  const int bRow = (wc * 32 + l15) * 128;

  bf16x8 bfr[2][2];
  bf16x8 af[2][2];

  // prologue: tile0 A+B complete, tile1 B in flight
  ST2_A(0, 0, 0); ST2_A(0, 1, 0); ST2_B(0, 0);
  ST2_B(1, 1);
  asm volatile("s_waitcnt vmcnt(2)" ::: "memory");
  BARR;

#pragma unroll 2
  for (int tile = 0; tile < NT - 2; ++tile) {
    TILE2_BODY(tile, tile & 1, true, true, 2);
  }
  TILE2_BODY(NT - 2, (NT - 2) & 1, true, false, 0);
  TILE2_BODY(NT - 1, (NT - 1) & 1, false, false, -1);

  // epilogue: row = m*16 + (lane>>4)*4 + r; rsacc[m][r] holds sum_k E[row,k]
  // on exactly this lane (all cols of the ones-MFMA D are identical).
  const int khi4 = (lane >> 4) * 4;
  int gc[2];
  float bv[2];
#pragma unroll
  for (int n = 0; n < 2; ++n) {
    gc[n] = colBase + wc * 32 + n * 16 + l15;
    bv[n] = (gc[n] < KK) ? bias[gc[n]] : 0.f;
  }
#pragma unroll
  for (int m = 0; m < 8; ++m) {
#pragma unroll
    for (int r = 0; r < 4; ++r) {
      const int grow = rowBase + wr * 128 + m * 16 + khi4 + r;
      const float inv = 1.0f / rsacc[m][r];
#pragma unroll
      for (int n = 0; n < 2; ++n) {
        if (gc[n] < KK)
          out[(size_t)grow * KK + gc[n]] = acc[m][n][r] * inv + bv[n];
      }
    }
  }
}

// ---- workspace layout (bytes) ----
#define OFF_XB 0u                    // 8192*2048*2 = 33554432
#define OFF_CB 33554432u             // 4096*2048*2 = 16777216
#define OFF_WB 50331648u             // 1024*4096*2 = 8388608
#define OFF_EB 58720256u             // 8192*4096*2 = 67108864
#define OFF_X2 125829120u            // 8192*4
#define OFF_C2 125861888u            // 4096*4

extern "C" void kernel_launch(void* const* d_in, const int* in_sizes, int n_in,
                              void* d_out, int out_size, void* d_ws, size_t ws_size,
                              hipStream_t stream) {
  const float* x = (const float*)d_in[0];
  const float* cen = (const float*)d_in[1];
  const float* beta = (const float*)d_in[2];
  const float* W = (const float*)d_in[3];
  const float* bias = (const float*)d_in[4];
  float* out = (float*)d_out;
  char* ws = (char*)d_ws;

  u16* xb = (u16*)(ws + OFF_XB);
  u16* cb = (u16*)(ws + OFF_CB);
  u16* wb = (u16*)(ws + OFF_WB);
  u16* eb = (u16*)(ws + OFF_EB);
  float* x2 = (float*)(ws + OFF_X2);
  float* c2 = (float*)(ws + OFF_C2);

  prep_all<<<BB + CC + KP, 256, 0, stream>>>(x, cen, W, xb, cb, wb, x2, c2);
  gemm1_rbf<<<dim3(CC / 256, BB / 256), 512, 0, stream>>>(xb, cb, x2, c2, beta, eb);
  gemm2_out<<<dim3(KP / 128, BB / 256), 512, 0, stream>>>(eb, wb, bias, out);
}

// Round 4
// 345.688 us; speedup vs baseline: 1.0929x; 1.0255x over previous
//
#include <hip/hip_runtime.h>

// ShallowRBF: x(8192x2048), centers(4096x2048), beta(4096), W(1000x4096), b(1000)
// out = (exp(-beta*||x-c||) @ W^T) / rowsum + b
//
// R7: (1) gemm2 back to 8 product MFMA/phase (ones-MFMA cost +19us: MFMA pipe
// saturated inside setprio window). (2) rowsum = contention-free partials from
// gemm1 epilogue (psum[row][bx*4+wc] in the dead `out` buffer) + tiny reduce
// kernel. (3) gemm2 XCD swizzle: co-locate the 8 blocks sharing an E-band on
// one XCD (default mapping put XCD=bx -> every XCD streamed all 67MB of E).

#define BB 8192
#define DD 2048
#define CC 4096
#define KK 1000
#define KP 1024

typedef unsigned short u16;
typedef __bf16 bf16x8 __attribute__((ext_vector_type(8)));
typedef float f32x4 __attribute__((ext_vector_type(4)));

typedef const void __attribute__((address_space(1)))* gvp_t;
typedef void __attribute__((address_space(3)))* lvp_t;

__device__ __forceinline__ u16 f2bf(float f) {
  union { float f; unsigned u; } v; v.f = f;
  return (u16)((v.u + 0x7fffu + ((v.u >> 16) & 1u)) >> 16);  // RNE
}

// ---- prep (fused): row norms + bf16 casts of x, centers; W cast+pad ----
__global__ void prep_all(const float* __restrict__ x, const float* __restrict__ cen,
                         const float* __restrict__ W,
                         u16* __restrict__ xb, u16* __restrict__ cb,
                         u16* __restrict__ wb,
                         float* __restrict__ x2, float* __restrict__ c2) {
  int row = blockIdx.x;
  int t = threadIdx.x;
  if (row >= BB + CC) {  // W rows (padded to KP with zeros)
    int r = row - BB - CC;
    ushort4* dst = reinterpret_cast<ushort4*>(wb + (size_t)r * CC);
    if (r < KK) {
      const float4* src = reinterpret_cast<const float4*>(W + (size_t)r * CC);
#pragma unroll
      for (int m = 0; m < 4; ++m) {
        float4 v = src[t + 256 * m];
        dst[t + 256 * m] = make_ushort4(f2bf(v.x), f2bf(v.y), f2bf(v.z), f2bf(v.w));
      }
    } else {
#pragma unroll
      for (int m = 0; m < 4; ++m) dst[t + 256 * m] = make_ushort4(0, 0, 0, 0);
    }
    return;
  }
  const float* src;
  u16* dst;
  float* nrm;
  if (row < BB) {
    src = x + (size_t)row * DD; dst = xb + (size_t)row * DD; nrm = x2 + row;
  } else {
    int r = row - BB;
    src = cen + (size_t)r * DD; dst = cb + (size_t)r * DD; nrm = c2 + r;
  }
  float s = 0.f;
#pragma unroll
  for (int m = 0; m < 2; ++m) {
    int idx = t + 256 * m;
    float4 v = reinterpret_cast<const float4*>(src)[idx];
    s += v.x * v.x + v.y * v.y + v.z * v.z + v.w * v.w;
    reinterpret_cast<ushort4*>(dst)[idx] =
        make_ushort4(f2bf(v.x), f2bf(v.y), f2bf(v.z), f2bf(v.w));
  }
#pragma unroll
  for (int off = 1; off < 64; off <<= 1) s += __shfl_xor(s, off);
  __shared__ float red[4];
  if ((t & 63) == 0) red[t >> 6] = s;
  __syncthreads();
  if (t == 0) *nrm = red[0] + red[1] + red[2] + red[3];
}

// ======================= shared schedule helpers =======================
#define SB0 __builtin_amdgcn_sched_barrier(0)
#define BARR __builtin_amdgcn_s_barrier()
#define LGKM0 asm volatile("s_waitcnt lgkmcnt(0)" ::: "memory")

// ======================= GEMM1: 256x256 8-phase =======================
// LDS/buffer (64KB): A 256x64 bf16 @0, B 256x64 @32768. Row=128B; logical
// chunk s of row r at phys chunk s^(r&7). Linear gload_lds dest +
// pre-swizzled global source.

#define ST_A(BUF, H, TILE)                                                         \
  {                                                                                \
    const u16* _s = gA0 + (size_t)((H) * 128) * DD + (TILE) * 64;                  \
    char* _d = (char*)smem + (BUF) * 65536 + (H) * 16384 + t * 16;                 \
    __builtin_amdgcn_global_load_lds((gvp_t)_s, (lvp_t)_d, 16, 0, 0);              \
    __builtin_amdgcn_global_load_lds((gvp_t)(_s + (size_t)64 * DD),                \
                                     (lvp_t)(_d + 8192), 16, 0, 0);                \
  }

#define ST_B(BUF, H, TILE)                                                         \
  {                                                                                \
    const u16* _s = gB0 + (size_t)((H) * 128) * DD + (TILE) * 64;                  \
    char* _d = (char*)smem + (BUF) * 65536 + 32768 + (H) * 16384 + t * 16;         \
    __builtin_amdgcn_global_load_lds((gvp_t)_s, (lvp_t)_d, 16, 0, 0);              \
    __builtin_amdgcn_global_load_lds((gvp_t)(_s + (size_t)64 * DD),                \
                                     (lvp_t)(_d + 8192), 16, 0, 0);                \
  }

#define READ_B(SBP)                                                                \
  _Pragma("unroll") for (int n_ = 0; n_ < 4; ++n_) {                               \
    _Pragma("unroll") for (int ks_ = 0; ks_ < 2; ++ks_) {                          \
      bfr[n_][ks_] = *(const bf16x8*)((SBP) + bRow + n_ * 2048 + cbv[ks_]);        \
    }                                                                              \
  }

#define READ_A(SAP, MQ)                                                            \
  _Pragma("unroll") for (int m_ = 0; m_ < 2; ++m_) {                               \
    _Pragma("unroll") for (int ks_ = 0; ks_ < 2; ++ks_) {                          \
      af[m_][ks_] =                                                                \
          *(const bf16x8*)((SAP) + aRow + ((MQ)*2 + m_) * 2048 + cbv[ks_]);        \
    }                                                                              \
  }

#define MFMA_Q(MQ)                                                                 \
  __builtin_amdgcn_s_setprio(1);                                                   \
  _Pragma("unroll") for (int m_ = 0; m_ < 2; ++m_) {                               \
    _Pragma("unroll") for (int n_ = 0; n_ < 4; ++n_) {                             \
      _Pragma("unroll") for (int ks_ = 0; ks_ < 2; ++ks_) {                        \
        acc[(MQ)*2 + m_][n_] = __builtin_amdgcn_mfma_f32_16x16x32_bf16(            \
            af[m_][ks_], bfr[n_][ks_], acc[(MQ)*2 + m_][n_], 0, 0, 0);             \
      }                                                                            \
    }                                                                              \
  }                                                                                \
  __builtin_amdgcn_s_setprio(0)

#define TILE_BODY(TILE, CUR, DOA, DOB, VMN)                                        \
  {                                                                                \
    const char* sA_ = (const char*)smem + (CUR) * 65536;                           \
    const char* sB_ = sA_ + 32768;                                                 \
    READ_B(sB_);                                                                   \
    READ_A(sA_, 0);                                                               \
    SB0;                                                                           \
    if (DOA) { ST_A(1 - (CUR), 0, (TILE) + 1); ST_A(1 - (CUR), 1, (TILE) + 1); }   \
    SB0; BARR; LGKM0; SB0;                                                         \
    MFMA_Q(0); SB0; BARR;                                                          \
    READ_A(sA_, 1); SB0;                                                           \
    if (DOB) { ST_B((CUR), 0, (TILE) + 2); }                                       \
    SB0; BARR; LGKM0; SB0;                                                         \
    MFMA_Q(1); SB0; BARR;                                                          \
    READ_A(sA_, 2); SB0;                                                           \
    if (DOB) { ST_B((CUR), 1, (TILE) + 2); }                                       \
    SB0; BARR; LGKM0; SB0;                                                         \
    MFMA_Q(2); SB0; BARR;                                                          \
    READ_A(sA_, 3); SB0; BARR; LGKM0; SB0;                                         \
    MFMA_Q(3);                                                                     \
    if ((VMN) == 4) { asm volatile("s_waitcnt vmcnt(4)" ::: "memory"); }           \
    else if ((VMN) == 0) { asm volatile("s_waitcnt vmcnt(0)" ::: "memory"); }      \
    SB0; BARR;                                                                     \
  }

__global__ __launch_bounds__(512, 2)
void gemm1_rbf(const u16* __restrict__ Abf, const u16* __restrict__ Bbf,
               const float* __restrict__ x2, const float* __restrict__ c2,
               const float* __restrict__ beta, u16* __restrict__ Ebf,
               float* __restrict__ psum) {
  constexpr int NT = DD / 64;  // 32 K-tiles
  __shared__ __align__(16) char smem[131072];

  const int t = threadIdx.x;
  const int lane = t & 63;
  const int wave = t >> 6;
  const int wr = wave >> 2;  // 0..1: rows wr*128..
  const int wc = wave & 3;   // 0..3: cols wc*64..
  const int l15 = lane & 15;

  const int rowBase = blockIdx.y * 256;
  const int colBase = blockIdx.x * 256;

  f32x4 acc[8][4];
#pragma unroll
  for (int i = 0; i < 8; ++i)
#pragma unroll
    for (int j = 0; j < 4; ++j) acc[i][j] = 0.f;

  // staging source (pre-swizzled logical chunk)
  const int srow = t >> 3;
  const u16* gA0 = Abf + (size_t)(rowBase + srow) * DD + ((t & 7) ^ (srow & 7)) * 8;
  const u16* gB0 = Bbf + (size_t)(colBase + srow) * DD + ((t & 7) ^ (srow & 7)) * 8;

  // frag-read byte column per kstep: phys chunk = (ks*4 + l>>4) ^ (l&7)
  int cbv[2];
  cbv[0] = (((lane >> 4) & 3) ^ (lane & 7)) << 4;
  cbv[1] = ((4 + ((lane >> 4) & 3)) ^ (lane & 7)) << 4;
  const int aRow = (wr * 128 + l15) * 128;
  const int bRow = (wc * 64 + l15) * 128;

  bf16x8 bfr[4][2];
  bf16x8 af[2][2];

  // prologue: tile0 complete + tile1 B-halves in flight
  ST_A(0, 0, 0); ST_A(0, 1, 0); ST_B(0, 0, 0); ST_B(0, 1, 0);
  ST_B(1, 0, 1); ST_B(1, 1, 1);
  asm volatile("s_waitcnt vmcnt(4)" ::: "memory");
  BARR;

#pragma unroll 2
  for (int tile = 0; tile < NT - 2; ++tile) {
    TILE_BODY(tile, tile & 1, true, true, 4);
  }
  TILE_BODY(NT - 2, (NT - 2) & 1, true, false, 0);
  TILE_BODY(NT - 1, (NT - 1) & 1, false, false, -1);

  // epilogue: C/D layout (16x16): col = lane&15, row = (lane>>4)*4 + reg
  const int khi4 = (lane >> 4) * 4;
  const int pslot = (blockIdx.x << 2) + wc;  // 0..63
  float c2v[4], bet[4];
  int gc[4];
#pragma unroll
  for (int n = 0; n < 4; ++n) {
    gc[n] = colBase + wc * 64 + n * 16 + l15;
    c2v[n] = c2[gc[n]];
    bet[n] = beta[gc[n]];
  }
#pragma unroll
  for (int m = 0; m < 8; ++m) {
#pragma unroll
    for (int r = 0; r < 4; ++r) {
      const int grow = rowBase + wr * 128 + m * 16 + khi4 + r;
      const float x2v = x2[grow];
      u16* orow = Ebf + (size_t)grow * CC;
      float rs = 0.f;
#pragma unroll
      for (int n = 0; n < 4; ++n) {
        float d = acc[m][n][r];
        float sq = fmaxf(x2v + c2v[n] - 2.0f * d, 0.0f);
        float e = __expf(-bet[n] * __builtin_amdgcn_sqrtf(sq));
        rs += e;
        orow[gc[n]] = f2bf(e);
      }
      // partial rowsum over this wave's 64-col quarter (16-lane reduce),
      // contention-free scatter: one f32 per (row, block-col, wave-col).
#pragma unroll
      for (int off = 1; off < 16; off <<= 1) rs += __shfl_xor(rs, off);
      if (l15 == 0) psum[(size_t)grow * 64 + pslot] = rs;
    }
  }
}

// ---- rowsum reduce: rowsum[r] = sum of psum[r][0..63] (2MB read) ----
__global__ void rowsum_reduce(const float* __restrict__ psum, float* __restrict__ rowsum) {
  const int row = blockIdx.x * 256 + threadIdx.x;
  const float4* p = reinterpret_cast<const float4*>(psum + (size_t)row * 64);
  float s = 0.f;
#pragma unroll
  for (int i = 0; i < 16; ++i) {
    float4 v = p[i];
    s += v.x + v.y + v.z + v.w;
  }
  rowsum[row] = s;
}

// ============ GEMM2: 256x128 8-phase; out = (E @ W^T)/rowsum + bias ============
// LDS/buffer (48KB): A 256x64 bf16 (32KB) @0, B 128x64 (16KB) @32768.
// Same swizzle. Staging: A-halves of t+1 at ph0/ph1, B of t+2 at ph2;
// boundary vmcnt(2). Per-wave out 128x32 (2Mx4N waves), 8 MFMA/phase.
// XCD-aware block remap: co-locate the 8 col-blocks of one E-band per XCD.

#define ST2_A(BUF, H, TILE)                                                        \
  {                                                                                \
    const u16* _s = gA0 + (size_t)((H) * 128) * CC + (TILE) * 64;                  \
    char* _d = (char*)smem + (BUF) * 49152 + (H) * 16384 + t * 16;                 \
    __builtin_amdgcn_global_load_lds((gvp_t)_s, (lvp_t)_d, 16, 0, 0);              \
    __builtin_amdgcn_global_load_lds((gvp_t)(_s + (size_t)64 * CC),                \
                                     (lvp_t)(_d + 8192), 16, 0, 0);                \
  }

#define ST2_B(BUF, TILE)                                                           \
  {                                                                                \
    const u16* _s = gB0 + (TILE) * 64;                                             \
    char* _d = (char*)smem + (BUF) * 49152 + 32768 + t * 16;                       \
    __builtin_amdgcn_global_load_lds((gvp_t)_s, (lvp_t)_d, 16, 0, 0);              \
    __builtin_amdgcn_global_load_lds((gvp_t)(_s + (size_t)64 * CC),                \
                                     (lvp_t)(_d + 8192), 16, 0, 0);                \
  }

#define READ2_B(SBP)                                                               \
  _Pragma("unroll") for (int n_ = 0; n_ < 2; ++n_) {                               \
    _Pragma("unroll") for (int ks_ = 0; ks_ < 2; ++ks_) {                          \
      bfr[n_][ks_] = *(const bf16x8*)((SBP) + bRow + n_ * 2048 + cbv[ks_]);        \
    }                                                                              \
  }

#define READ2_A(SAP, MQ)                                                           \
  _Pragma("unroll") for (int m_ = 0; m_ < 2; ++m_) {                               \
    _Pragma("unroll") for (int ks_ = 0; ks_ < 2; ++ks_) {                          \
      af[m_][ks_] =                                                                \
          *(const bf16x8*)((SAP) + aRow + ((MQ)*2 + m_) * 2048 + cbv[ks_]);        \
    }                                                                              \
  }

#define MFMA2_Q(MQ)                                                                \
  __builtin_amdgcn_s_setprio(1);                                                   \
  _Pragma("unroll") for (int m_ = 0; m_ < 2; ++m_) {                               \
    _Pragma("unroll") for (int n_ = 0; n_ < 2; ++n_) {                             \
      _Pragma("unroll") for (int ks_ = 0; ks_ < 2; ++ks_) {                        \
        acc[(MQ)*2 + m_][n_] = __builtin_amdgcn_mfma_f32_16x16x32_bf16(            \
            af[m_][ks_], bfr[n_][ks_], acc[(MQ)*2 + m_][n_], 0, 0, 0);             \
      }                                                                            \
    }                                                                              \
  }                                                                                \
  __builtin_amdgcn_s_setprio(0)

#define TILE2_BODY(TILE, CUR, DOA, DOB, VMN)                                       \
  {                                                                                \
    const char* sA_ = (const char*)smem + (CUR) * 49152;                           \
    const char* sB_ = sA_ + 32768;                                                 \
    READ2_B(sB_);                                                                  \
    READ2_A(sA_, 0);                                                               \
    SB0;                                                                           \
    if (DOA) { ST2_A(1 - (CUR), 0, (TILE) + 1); }                                  \
    SB0; BARR; LGKM0; SB0;                                                         \
    MFMA2_Q(0); SB0; BARR;                                                         \
    READ2_A(sA_, 1); SB0;                                                          \
    if (DOA) { ST2_A(1 - (CUR), 1, (TILE) + 1); }                                  \
    SB0; BARR; LGKM0; SB0;                                                         \
    MFMA2_Q(1); SB0; BARR;                                                         \
    READ2_A(sA_, 2); SB0;                                                          \
    if (DOB) { ST2_B((CUR), (TILE) + 2); }                                         \
    SB0; BARR; LGKM0; SB0;                                                         \
    MFMA2_Q(2); SB0; BARR;                                                         \
    READ2_A(sA_, 3); SB0; BARR; LGKM0; SB0;                                        \
    MFMA2_Q(3);                                                                    \
    if ((VMN) == 2) { asm volatile("s_waitcnt vmcnt(2)" ::: "memory"); }           \
    else if ((VMN) == 0) { asm volatile("s_waitcnt vmcnt(0)" ::: "memory"); }      \
    SB0; BARR;                                                                     \
  }

__global__ __launch_bounds__(512, 2)
void gemm2_out(const u16* __restrict__ Ebf, const u16* __restrict__ Wbf,
               const float* __restrict__ rowsum, const float* __restrict__ bias,
               float* __restrict__ out) {
  constexpr int NT = CC / 64;  // 64 K-tiles
  __shared__ __align__(16) char smem[98304];

  const int t = threadIdx.x;
  const int lane = t & 63;
  const int wave = t >> 6;
  const int wr = wave >> 2;  // 0..1: rows wr*128..
  const int wc = wave & 3;   // 0..3: cols wc*32..
  const int l15 = lane & 15;

  // XCD-aware remap (bijective on 256 blocks): dispatch d -> XCD d%8.
  // Put the 8 col-blocks of E-band `by` on XCD by%8 so the band's K-slices
  // are fetched into one L2 and hit 8x (default: XCD=bx -> each XCD
  // streamed all of E).
  const int d = blockIdx.x + (blockIdx.y << 3);
  const int s_ = d >> 3;
  const int by = (d & 7) + ((s_ >> 3) << 3);
  const int bx = s_ & 7;

  const int rowBase = by * 256;
  const int colBase = bx * 128;

  f32x4 acc[8][2];
#pragma unroll
  for (int i = 0; i < 8; ++i)
#pragma unroll
    for (int j = 0; j < 2; ++j) acc[i][j] = 0.f;

  const int srow = t >> 3;
  const u16* gA0 = Ebf + (size_t)(rowBase + srow) * CC + ((t & 7) ^ (srow & 7)) * 8;
  const u16* gB0 = Wbf + (size_t)(colBase + srow) * CC + ((t & 7) ^ (srow & 7)) * 8;

  int cbv[2];
  cbv[0] = (((lane >> 4) & 3) ^ (lane & 7)) << 4;
  cbv[1] = ((4 + ((lane >> 4) & 3)) ^ (lane & 7)) << 4;
  const int aRow = (wr * 128 + l15) * 128;
  const int bRow = (wc * 32 + l15) * 128;

  bf16x8 bfr[2][2];
  bf16x8 af[2][2];

  // prologue: tile0 A+B complete, tile1 B in flight
  ST2_A(0, 0, 0); ST2_A(0, 1, 0); ST2_B(0, 0);
  ST2_B(1, 1);
  asm volatile("s_waitcnt vmcnt(2)" ::: "memory");
  BARR;

#pragma unroll 2
  for (int tile = 0; tile < NT - 2; ++tile) {
    TILE2_BODY(tile, tile & 1, true, true, 2);
  }
  TILE2_BODY(NT - 2, (NT - 2) & 1, true, false, 0);
  TILE2_BODY(NT - 1, (NT - 1) & 1, false, false, -1);

  // epilogue
  const int khi4 = (lane >> 4) * 4;
  int gc[2];
  float bv[2];
#pragma unroll
  for (int n = 0; n < 2; ++n) {
    gc[n] = colBase + wc * 32 + n * 16 + l15;
    bv[n] = (gc[n] < KK) ? bias[gc[n]] : 0.f;
  }
#pragma unroll
  for (int m = 0; m < 8; ++m) {
#pragma unroll
    for (int r = 0; r < 4; ++r) {
      const int grow = rowBase + wr * 128 + m * 16 + khi4 + r;
      const float inv = 1.0f / rowsum[grow];
#pragma unroll
      for (int n = 0; n < 2; ++n) {
        if (gc[n] < KK)
          out[(size_t)grow * KK + gc[n]] = acc[m][n][r] * inv + bv[n];
      }
    }
  }
}

// ---- workspace layout (bytes) ----
#define OFF_XB 0u                    // 8192*2048*2 = 33554432
#define OFF_CB 33554432u             // 4096*2048*2 = 16777216
#define OFF_WB 50331648u             // 1024*4096*2 = 8388608
#define OFF_EB 58720256u             // 8192*4096*2 = 67108864
#define OFF_X2 125829120u            // 8192*4
#define OFF_C2 125861888u            // 4096*4
#define OFF_RS 125878272u            // 8192*4

extern "C" void kernel_launch(void* const* d_in, const int* in_sizes, int n_in,
                              void* d_out, int out_size, void* d_ws, size_t ws_size,
                              hipStream_t stream) {
  const float* x = (const float*)d_in[0];
  const float* cen = (const float*)d_in[1];
  const float* beta = (const float*)d_in[2];
  const float* W = (const float*)d_in[3];
  const float* bias = (const float*)d_in[4];
  float* out = (float*)d_out;
  char* ws = (char*)d_ws;

  u16* xb = (u16*)(ws + OFF_XB);
  u16* cb = (u16*)(ws + OFF_CB);
  u16* wb = (u16*)(ws + OFF_WB);
  u16* eb = (u16*)(ws + OFF_EB);
  float* x2 = (float*)(ws + OFF_X2);
  float* c2 = (float*)(ws + OFF_C2);
  float* rowsum = (float*)(ws + OFF_RS);
  float* psum = out;  // 8192*64*4 = 2MB scratch in the (dead until gemm2) out buffer

  prep_all<<<BB + CC + KP, 256, 0, stream>>>(x, cen, W, xb, cb, wb, x2, c2);
  gemm1_rbf<<<dim3(CC / 256, BB / 256), 512, 0, stream>>>(xb, cb, x2, c2, beta, eb, psum);
  rowsum_reduce<<<BB / 256, 256, 0, stream>>>(psum, rowsum);
  gemm2_out<<<dim3(KP / 128, BB / 256), 512, 0, stream>>>(eb, wb, rowsum, bias, out);
}

// Round 5
// 337.641 us; speedup vs baseline: 1.1189x; 1.0238x over previous
//
#include <hip/hip_runtime.h>

// ShallowRBF: x(8192x2048), centers(4096x2048), beta(4096), W(1000x4096), b(1000)
// out = (exp(-beta*||x-c||) @ W^T) / rowsum + b
//
// R8: (1) barrier-minimal K-loop: 2 barriers/tile (ph0-end = ST_B-vs-ph0-read
// safety; boundary = staged-data visibility after counted vmcnt). All frag
// reads are own-wave (lgkmcnt per-wave); all other stage targets provably
// dead in the skew window. 64 MFMA / 2 barriers = AITER's density.
// (2) gemm1 rowsum partials via LDS (stride-68, conflict-free) + coalesced
// store to psum[16][8192] (in dead `out` buf); rowsum_reduce reads 512KB.

#define BB 8192
#define DD 2048
#define CC 4096
#define KK 1000
#define KP 1024

typedef unsigned short u16;
typedef __bf16 bf16x8 __attribute__((ext_vector_type(8)));
typedef float f32x4 __attribute__((ext_vector_type(4)));

typedef const void __attribute__((address_space(1)))* gvp_t;
typedef void __attribute__((address_space(3)))* lvp_t;

__device__ __forceinline__ u16 f2bf(float f) {
  union { float f; unsigned u; } v; v.f = f;
  return (u16)((v.u + 0x7fffu + ((v.u >> 16) & 1u)) >> 16);  // RNE
}

// ---- prep (fused): row norms + bf16 casts of x, centers; W cast+pad ----
__global__ void prep_all(const float* __restrict__ x, const float* __restrict__ cen,
                         const float* __restrict__ W,
                         u16* __restrict__ xb, u16* __restrict__ cb,
                         u16* __restrict__ wb,
                         float* __restrict__ x2, float* __restrict__ c2) {
  int row = blockIdx.x;
  int t = threadIdx.x;
  if (row >= BB + CC) {  // W rows (padded to KP with zeros)
    int r = row - BB - CC;
    ushort4* dst = reinterpret_cast<ushort4*>(wb + (size_t)r * CC);
    if (r < KK) {
      const float4* src = reinterpret_cast<const float4*>(W + (size_t)r * CC);
#pragma unroll
      for (int m = 0; m < 4; ++m) {
        float4 v = src[t + 256 * m];
        dst[t + 256 * m] = make_ushort4(f2bf(v.x), f2bf(v.y), f2bf(v.z), f2bf(v.w));
      }
    } else {
#pragma unroll
      for (int m = 0; m < 4; ++m) dst[t + 256 * m] = make_ushort4(0, 0, 0, 0);
    }
    return;
  }
  const float* src;
  u16* dst;
  float* nrm;
  if (row < BB) {
    src = x + (size_t)row * DD; dst = xb + (size_t)row * DD; nrm = x2 + row;
  } else {
    int r = row - BB;
    src = cen + (size_t)r * DD; dst = cb + (size_t)r * DD; nrm = c2 + r;
  }
  float s = 0.f;
#pragma unroll
  for (int m = 0; m < 2; ++m) {
    int idx = t + 256 * m;
    float4 v = reinterpret_cast<const float4*>(src)[idx];
    s += v.x * v.x + v.y * v.y + v.z * v.z + v.w * v.w;
    reinterpret_cast<ushort4*>(dst)[idx] =
        make_ushort4(f2bf(v.x), f2bf(v.y), f2bf(v.z), f2bf(v.w));
  }
#pragma unroll
  for (int off = 1; off < 64; off <<= 1) s += __shfl_xor(s, off);
  __shared__ float red[4];
  if ((t & 63) == 0) red[t >> 6] = s;
  __syncthreads();
  if (t == 0) *nrm = red[0] + red[1] + red[2] + red[3];
}

// ======================= shared schedule helpers =======================
#define SB0 __builtin_amdgcn_sched_barrier(0)
#define BARR __builtin_amdgcn_s_barrier()
#define LGKM0 asm volatile("s_waitcnt lgkmcnt(0)" ::: "memory")

// ======================= GEMM1: 256x256, 2 barriers/tile =======================
// LDS/buffer (64KB): A 256x64 bf16 @0, B 256x64 @32768. Row=128B; logical
// chunk s of row r at phys chunk s^(r&7). Linear gload_lds dest +
// pre-swizzled global source.

#define ST_A(BUF, H, TILE)                                                         \
  {                                                                                \
    const u16* _s = gA0 + (size_t)((H) * 128) * DD + (TILE) * 64;                  \
    char* _d = (char*)smem + (BUF) * 65536 + (H) * 16384 + t * 16;                 \
    __builtin_amdgcn_global_load_lds((gvp_t)_s, (lvp_t)_d, 16, 0, 0);              \
    __builtin_amdgcn_global_load_lds((gvp_t)(_s + (size_t)64 * DD),                \
                                     (lvp_t)(_d + 8192), 16, 0, 0);                \
  }

#define ST_B(BUF, H, TILE)                                                         \
  {                                                                                \
    const u16* _s = gB0 + (size_t)((H) * 128) * DD + (TILE) * 64;                  \
    char* _d = (char*)smem + (BUF) * 65536 + 32768 + (H) * 16384 + t * 16;         \
    __builtin_amdgcn_global_load_lds((gvp_t)_s, (lvp_t)_d, 16, 0, 0);              \
    __builtin_amdgcn_global_load_lds((gvp_t)(_s + (size_t)64 * DD),                \
                                     (lvp_t)(_d + 8192), 16, 0, 0);                \
  }

#define READ_B(SBP)                                                                \
  _Pragma("unroll") for (int n_ = 0; n_ < 4; ++n_) {                               \
    _Pragma("unroll") for (int ks_ = 0; ks_ < 2; ++ks_) {                          \
      bfr[n_][ks_] = *(const bf16x8*)((SBP) + bRow + n_ * 2048 + cbv[ks_]);        \
    }                                                                              \
  }

#define READ_A(SAP, MQ)                                                            \
  _Pragma("unroll") for (int m_ = 0; m_ < 2; ++m_) {                               \
    _Pragma("unroll") for (int ks_ = 0; ks_ < 2; ++ks_) {                          \
      af[m_][ks_] =                                                                \
          *(const bf16x8*)((SAP) + aRow + ((MQ)*2 + m_) * 2048 + cbv[ks_]);        \
    }                                                                              \
  }

#define MFMA_Q(MQ)                                                                 \
  __builtin_amdgcn_s_setprio(1);                                                   \
  _Pragma("unroll") for (int m_ = 0; m_ < 2; ++m_) {                               \
    _Pragma("unroll") for (int n_ = 0; n_ < 4; ++n_) {                             \
      _Pragma("unroll") for (int ks_ = 0; ks_ < 2; ++ks_) {                        \
        acc[(MQ)*2 + m_][n_] = __builtin_amdgcn_mfma_f32_16x16x32_bf16(            \
            af[m_][ks_], bfr[n_][ks_], acc[(MQ)*2 + m_][n_], 0, 0, 0);             \
      }                                                                            \
    }                                                                              \
  }                                                                                \
  __builtin_amdgcn_s_setprio(0)

// 2 barriers per tile:
//  - ph0-end BARR: collective "all waves' B-cur reads done" before ST_B (ph1/2)
//  - boundary BARR (after counted vmcnt): staged tile+1 collectively visible
// Everything else is own-wave ordering via lgkmcnt(0) (per-wave counter).
#define TILE_BODY(TILE, CUR, DOA, DOB, VMN)                                        \
  {                                                                                \
    const char* sA_ = (const char*)smem + (CUR) * 65536;                           \
    const char* sB_ = sA_ + 32768;                                                 \
    READ_B(sB_);                                                                   \
    READ_A(sA_, 0);                                                                \
    SB0;                                                                           \
    if (DOA) { ST_A(1 - (CUR), 0, (TILE) + 1); ST_A(1 - (CUR), 1, (TILE) + 1); }   \
    SB0; LGKM0; SB0;                                                               \
    MFMA_Q(0); SB0; BARR;                                                          \
    READ_A(sA_, 1); SB0;                                                           \
    if (DOB) { ST_B((CUR), 0, (TILE) + 2); }                                       \
    SB0; LGKM0; SB0;                                                               \
    MFMA_Q(1); SB0;                                                                \
    READ_A(sA_, 2); SB0;                                                           \
    if (DOB) { ST_B((CUR), 1, (TILE) + 2); }                                       \
    SB0; LGKM0; SB0;                                                               \
    MFMA_Q(2); SB0;                                                                \
    READ_A(sA_, 3); SB0; LGKM0; SB0;                                               \
    MFMA_Q(3);                                                                     \
    if ((VMN) == 4) { asm volatile("s_waitcnt vmcnt(4)" ::: "memory"); }           \
    else if ((VMN) == 0) { asm volatile("s_waitcnt vmcnt(0)" ::: "memory"); }      \
    SB0; BARR;                                                                     \
  }

__global__ __launch_bounds__(512, 2)
void gemm1_rbf(const u16* __restrict__ Abf, const u16* __restrict__ Bbf,
               const float* __restrict__ x2, const float* __restrict__ c2,
               const float* __restrict__ beta, u16* __restrict__ Ebf,
               float* __restrict__ psum) {
  constexpr int NT = DD / 64;  // 32 K-tiles
  __shared__ __align__(16) char smem[131072];

  const int t = threadIdx.x;
  const int lane = t & 63;
  const int wave = t >> 6;
  const int wr = wave >> 2;  // 0..1: rows wr*128..
  const int wc = wave & 3;   // 0..3: cols wc*64..
  const int l15 = lane & 15;

  const int rowBase = blockIdx.y * 256;
  const int colBase = blockIdx.x * 256;

  f32x4 acc[8][4];
#pragma unroll
  for (int i = 0; i < 8; ++i)
#pragma unroll
    for (int j = 0; j < 4; ++j) acc[i][j] = 0.f;

  // staging source (pre-swizzled logical chunk)
  const int srow = t >> 3;
  const u16* gA0 = Abf + (size_t)(rowBase + srow) * DD + ((t & 7) ^ (srow & 7)) * 8;
  const u16* gB0 = Bbf + (size_t)(colBase + srow) * DD + ((t & 7) ^ (srow & 7)) * 8;

  // frag-read byte column per kstep: phys chunk = (ks*4 + l>>4) ^ (l&7)
  int cbv[2];
  cbv[0] = (((lane >> 4) & 3) ^ (lane & 7)) << 4;
  cbv[1] = ((4 + ((lane >> 4) & 3)) ^ (lane & 7)) << 4;
  const int aRow = (wr * 128 + l15) * 128;
  const int bRow = (wc * 64 + l15) * 128;

  bf16x8 bfr[4][2];
  bf16x8 af[2][2];

  // prologue: tile0 complete + tile1 B-halves in flight
  ST_A(0, 0, 0); ST_A(0, 1, 0); ST_B(0, 0, 0); ST_B(0, 1, 0);
  ST_B(1, 0, 1); ST_B(1, 1, 1);
  asm volatile("s_waitcnt vmcnt(4)" ::: "memory");
  BARR;

#pragma unroll 2
  for (int tile = 0; tile < NT - 2; ++tile) {
    TILE_BODY(tile, tile & 1, true, true, 4);
  }
  TILE_BODY(NT - 2, (NT - 2) & 1, true, false, 0);
  TILE_BODY(NT - 1, (NT - 1) & 1, false, false, -1);

  // epilogue: C/D layout (16x16): col = lane&15, row = (lane>>4)*4 + reg
  const int khi4 = (lane >> 4) * 4;
  float* lrs = (float*)smem;  // [256 rows][stride 68] f32 partials
  float c2v[4], bet[4];
  int gc[4];
#pragma unroll
  for (int n = 0; n < 4; ++n) {
    gc[n] = colBase + wc * 64 + n * 16 + l15;
    c2v[n] = c2[gc[n]];
    bet[n] = beta[gc[n]];
  }
#pragma unroll
  for (int m = 0; m < 8; ++m) {
#pragma unroll
    for (int r = 0; r < 4; ++r) {
      const int rrel = wr * 128 + m * 16 + khi4 + r;
      const int grow = rowBase + rrel;
      const float x2v = x2[grow];
      u16* orow = Ebf + (size_t)grow * CC;
      float rs = 0.f;
#pragma unroll
      for (int n = 0; n < 4; ++n) {
        float d = acc[m][n][r];
        float sq = fmaxf(x2v + c2v[n] - 2.0f * d, 0.0f);
        float e = __expf(-bet[n] * __builtin_amdgcn_sqrtf(sq));
        rs += e;
        orow[gc[n]] = f2bf(e);
      }
      lrs[rrel * 68 + wc * 16 + l15] = rs;  // conflict-free (stride-68 pad)
    }
  }
  __syncthreads();
  if (t < 256) {
    const f32x4* p = (const f32x4*)(lrs + t * 68);  // 272B stride, 16B-aligned
    float s = 0.f;
#pragma unroll
    for (int i = 0; i < 16; ++i) {
      f32x4 v = p[i];
      s += v[0] + v[1] + v[2] + v[3];
    }
    psum[(size_t)blockIdx.x * BB + rowBase + t] = s;  // coalesced
  }
}

// ---- rowsum reduce: rowsum[r] = sum_b psum[b][r]  (psum is [16][8192]) ----
__global__ void rowsum_reduce(const float* __restrict__ psum, float* __restrict__ rowsum) {
  const int row = blockIdx.x * 256 + threadIdx.x;
  float s = 0.f;
#pragma unroll
  for (int b = 0; b < 16; ++b) s += psum[(size_t)b * BB + row];
  rowsum[row] = s;
}

// ============ GEMM2: 256x128, 2 barriers/tile; out = (E @ W^T)/rowsum + b ============
// LDS/buffer (48KB): A 256x64 bf16 (32KB) @0, B 128x64 (16KB) @32768.
// Staging: A-halves of t+1 at ph0/ph1 (other buffer), B of t+2 at ph2 (cur
// buffer, dead after ph0 reads -> guarded by ph0-end BARR); boundary vmcnt(2).
// XCD-aware remap: co-locate the 8 col-blocks of one E-band per XCD.

#define ST2_A(BUF, H, TILE)                                                        \
  {                                                                                \
    const u16* _s = gA0 + (size_t)((H) * 128) * CC + (TILE) * 64;                  \
    char* _d = (char*)smem + (BUF) * 49152 + (H) * 16384 + t * 16;                 \
    __builtin_amdgcn_global_load_lds((gvp_t)_s, (lvp_t)_d, 16, 0, 0);              \
    __builtin_amdgcn_global_load_lds((gvp_t)(_s + (size_t)64 * CC),                \
                                     (lvp_t)(_d + 8192), 16, 0, 0);                \
  }

#define ST2_B(BUF, TILE)                                                           \
  {                                                                                \
    const u16* _s = gB0 + (TILE) * 64;                                             \
    char* _d = (char*)smem + (BUF) * 49152 + 32768 + t * 16;                       \
    __builtin_amdgcn_global_load_lds((gvp_t)_s, (lvp_t)_d, 16, 0, 0);              \
    __builtin_amdgcn_global_load_lds((gvp_t)(_s + (size_t)64 * CC),                \
                                     (lvp_t)(_d + 8192), 16, 0, 0);                \
  }

#define READ2_B(SBP)                                                               \
  _Pragma("unroll") for (int n_ = 0; n_ < 2; ++n_) {                               \
    _Pragma("unroll") for (int ks_ = 0; ks_ < 2; ++ks_) {                          \
      bfr[n_][ks_] = *(const bf16x8*)((SBP) + bRow + n_ * 2048 + cbv[ks_]);        \
    }                                                                              \
  }

#define READ2_A(SAP, MQ)                                                           \
  _Pragma("unroll") for (int m_ = 0; m_ < 2; ++m_) {                               \
    _Pragma("unroll") for (int ks_ = 0; ks_ < 2; ++ks_) {                          \
      af[m_][ks_] =                                                                \
          *(const bf16x8*)((SAP) + aRow + ((MQ)*2 + m_) * 2048 + cbv[ks_]);        \
    }                                                                              \
  }

#define MFMA2_Q(MQ)                                                                \
  __builtin_amdgcn_s_setprio(1);                                                   \
  _Pragma("unroll") for (int m_ = 0; m_ < 2; ++m_) {                               \
    _Pragma("unroll") for (int n_ = 0; n_ < 2; ++n_) {                             \
      _Pragma("unroll") for (int ks_ = 0; ks_ < 2; ++ks_) {                        \
        acc[(MQ)*2 + m_][n_] = __builtin_amdgcn_mfma_f32_16x16x32_bf16(            \
            af[m_][ks_], bfr[n_][ks_], acc[(MQ)*2 + m_][n_], 0, 0, 0);             \
      }                                                                            \
    }                                                                              \
  }                                                                                \
  __builtin_amdgcn_s_setprio(0)

#define TILE2_BODY(TILE, CUR, DOA, DOB, VMN)                                       \
  {                                                                                \
    const char* sA_ = (const char*)smem + (CUR) * 49152;                           \
    const char* sB_ = sA_ + 32768;                                                 \
    READ2_B(sB_);                                                                  \
    READ2_A(sA_, 0);                                                               \
    SB0;                                                                           \
    if (DOA) { ST2_A(1 - (CUR), 0, (TILE) + 1); }                                  \
    SB0; LGKM0; SB0;                                                               \
    MFMA2_Q(0); SB0; BARR;                                                         \
    READ2_A(sA_, 1); SB0;                                                          \
    if (DOA) { ST2_A(1 - (CUR), 1, (TILE) + 1); }                                  \
    SB0; LGKM0; SB0;                                                               \
    MFMA2_Q(1); SB0;                                                               \
    READ2_A(sA_, 2); SB0;                                                          \
    if (DOB) { ST2_B((CUR), (TILE) + 2); }                                         \
    SB0; LGKM0; SB0;                                                               \
    MFMA2_Q(2); SB0;                                                               \
    READ2_A(sA_, 3); SB0; LGKM0; SB0;                                              \
    MFMA2_Q(3);                                                                    \
    if ((VMN) == 2) { asm volatile("s_waitcnt vmcnt(2)" ::: "memory"); }           \
    else if ((VMN) == 0) { asm volatile("s_waitcnt vmcnt(0)" ::: "memory"); }      \
    SB0; BARR;                                                                     \
  }

__global__ __launch_bounds__(512, 2)
void gemm2_out(const u16* __restrict__ Ebf, const u16* __restrict__ Wbf,
               const float* __restrict__ rowsum, const float* __restrict__ bias,
               float* __restrict__ out) {
  constexpr int NT = CC / 64;  // 64 K-tiles
  __shared__ __align__(16) char smem[98304];

  const int t = threadIdx.x;
  const int lane = t & 63;
  const int wave = t >> 6;
  const int wr = wave >> 2;  // 0..1: rows wr*128..
  const int wc = wave & 3;   // 0..3: cols wc*32..
  const int l15 = lane & 15;

  // XCD-aware remap (bijective on 256 blocks): dispatch d -> XCD d%8.
  const int d = blockIdx.x + (blockIdx.y << 3);
  const int s_ = d >> 3;
  const int by = (d & 7) + ((s_ >> 3) << 3);
  const int bx = s_ & 7;

  const int rowBase = by * 256;
  const int colBase = bx * 128;

  f32x4 acc[8][2];
#pragma unroll
  for (int i = 0; i < 8; ++i)
#pragma unroll
    for (int j = 0; j < 2; ++j) acc[i][j] = 0.f;

  const int srow = t >> 3;
  const u16* gA0 = Ebf + (size_t)(rowBase + srow) * CC + ((t & 7) ^ (srow & 7)) * 8;
  const u16* gB0 = Wbf + (size_t)(colBase + srow) * CC + ((t & 7) ^ (srow & 7)) * 8;

  int cbv[2];
  cbv[0] = (((lane >> 4) & 3) ^ (lane & 7)) << 4;
  cbv[1] = ((4 + ((lane >> 4) & 3)) ^ (lane & 7)) << 4;
  const int aRow = (wr * 128 + l15) * 128;
  const int bRow = (wc * 32 + l15) * 128;

  bf16x8 bfr[2][2];
  bf16x8 af[2][2];

  // prologue: tile0 A+B complete, tile1 B in flight
  ST2_A(0, 0, 0); ST2_A(0, 1, 0); ST2_B(0, 0);
  ST2_B(1, 1);
  asm volatile("s_waitcnt vmcnt(2)" ::: "memory");
  BARR;

#pragma unroll 2
  for (int tile = 0; tile < NT - 2; ++tile) {
    TILE2_BODY(tile, tile & 1, true, true, 2);
  }
  TILE2_BODY(NT - 2, (NT - 2) & 1, true, false, 0);
  TILE2_BODY(NT - 1, (NT - 1) & 1, false, false, -1);

  // epilogue
  const int khi4 = (lane >> 4) * 4;
  int gc[2];
  float bv[2];
#pragma unroll
  for (int n = 0; n < 2; ++n) {
    gc[n] = colBase + wc * 32 + n * 16 + l15;
    bv[n] = (gc[n] < KK) ? bias[gc[n]] : 0.f;
  }
#pragma unroll
  for (int m = 0; m < 8; ++m) {
#pragma unroll
    for (int r = 0; r < 4; ++r) {
      const int grow = rowBase + wr * 128 + m * 16 + khi4 + r;
      const float inv = 1.0f / rowsum[grow];
#pragma unroll
      for (int n = 0; n < 2; ++n) {
        if (gc[n] < KK)
          out[(size_t)grow * KK + gc[n]] = acc[m][n][r] * inv + bv[n];
      }
    }
  }
}

// ---- workspace layout (bytes) ----
#define OFF_XB 0u                    // 8192*2048*2 = 33554432
#define OFF_CB 33554432u             // 4096*2048*2 = 16777216
#define OFF_WB 50331648u             // 1024*4096*2 = 8388608
#define OFF_EB 58720256u             // 8192*4096*2 = 67108864
#define OFF_X2 125829120u            // 8192*4
#define OFF_C2 125861888u            // 4096*4
#define OFF_RS 125878272u            // 8192*4

extern "C" void kernel_launch(void* const* d_in, const int* in_sizes, int n_in,
                              void* d_out, int out_size, void* d_ws, size_t ws_size,
                              hipStream_t stream) {
  const float* x = (const float*)d_in[0];
  const float* cen = (const float*)d_in[1];
  const float* beta = (const float*)d_in[2];
  const float* W = (const float*)d_in[3];
  const float* bias = (const float*)d_in[4];
  float* out = (float*)d_out;
  char* ws = (char*)d_ws;

  u16* xb = (u16*)(ws + OFF_XB);
  u16* cb = (u16*)(ws + OFF_CB);
  u16* wb = (u16*)(ws + OFF_WB);
  u16* eb = (u16*)(ws + OFF_EB);
  float* x2 = (float*)(ws + OFF_X2);
  float* c2 = (float*)(ws + OFF_C2);
  float* rowsum = (float*)(ws + OFF_RS);
  float* psum = out;  // [16][8192] f32 = 512KB scratch in the (dead until gemm2) out buffer

  prep_all<<<BB + CC + KP, 256, 0, stream>>>(x, cen, W, xb, cb, wb, x2, c2);
  gemm1_rbf<<<dim3(CC / 256, BB / 256), 512, 0, stream>>>(xb, cb, x2, c2, beta, eb, psum);
  rowsum_reduce<<<BB / 256, 256, 0, stream>>>(psum, rowsum);
  gemm2_out<<<dim3(KP / 128, BB / 256), 512, 0, stream>>>(eb, wb, rowsum, bias, out);
}